// Round 3
// baseline (317.687 us; speedup 1.0000x reference)
//
#include <hip/hip_runtime.h>

typedef __bf16 bf16_t;
typedef __bf16 bf16x8 __attribute__((ext_vector_type(8)));
typedef __bf16 bf16x4 __attribute__((ext_vector_type(4)));
typedef float f32x4 __attribute__((ext_vector_type(4)));

#define MFMA16(a, b, c) __builtin_amdgcn_mfma_f32_16x16x32_bf16((a), (b), (c), 0, 0, 0)

namespace {
constexpr int S_LEN = 2048;
constexpr int EMB   = 1024;
constexpr int HEADS = 16;
constexpr int HD    = 64;
// Q is pre-scaled by log2(e)/sqrt(EMB) so attention scores are already in
// the log2 domain: softmax = exp2(sv - m), no per-element multiply.
constexpr float Q_PRESCALE = 1.44269504088896340736f / 32.0f;
constexpr float NEG_L2     = -4.5084e18f;   // -1e20 * log2(e)/32
constexpr float DEFER_THR  = 8.0f;          // T13: skip rescale if growth <= 8 (p <= 256)
}

// load 8 contiguous fp32 and round to bf16x8
__device__ __forceinline__ bf16x8 load8_cvt(const float* __restrict__ p) {
    const f32x4 a = *(const f32x4*)p;
    const f32x4 b = *(const f32x4*)(p + 4);
    bf16x8 r;
    r[0] = (bf16_t)a[0]; r[1] = (bf16_t)a[1]; r[2] = (bf16_t)a[2]; r[3] = (bf16_t)a[3];
    r[4] = (bf16_t)b[0]; r[5] = (bf16_t)b[1]; r[6] = (bf16_t)b[2]; r[7] = (bf16_t)b[3];
    return r;
}

// --------------------------------------------------------------------------
// Kernel 1: per-head projections (fp32 in -> bf16 out).
//   mat 0: Qp[nh][s][d]  = (queries @ Wq^T) * Q_PRESCALE
//   mat 1: Kp[nh][s][d]  = keys @ Wk^T
//   mat 2: VpT[nh][d][s] = (values @ Wv^T)^T
// --------------------------------------------------------------------------
__global__ __launch_bounds__(256) void proj_kernel(
    const float* __restrict__ values, const float* __restrict__ keys,
    const float* __restrict__ queries,
    const float* __restrict__ Wv, const float* __restrict__ Wk,
    const float* __restrict__ Wq,
    bf16_t* __restrict__ Qp, bf16_t* __restrict__ Kp, bf16_t* __restrict__ VpT)
{
    const int tid = threadIdx.x;
    const int w = tid >> 6, l = tid & 63, g = l >> 4, q15 = l & 15;
    const int b   = blockIdx.x;
    const int mat = b >> 10;          // 0=Q, 1=K, 2=V
    const int rem = b & 1023;
    const int h   = rem >> 6;
    const int t0  = (((rem & 63) << 2) + w) << 4;
    const int n   = t0 >> 11;
    const int s0  = t0 & 2047;

    if (mat < 2) {
        const float* X = (mat == 0) ? queries : keys;
        const float* W = (mat == 0) ? Wq : Wk;
        const float scl = (mat == 0) ? Q_PRESCALE : 1.0f;
        bf16_t* O = ((mat == 0) ? Qp : Kp) + (size_t)(n * HEADS + h) * S_LEN * HD;
        const float* xr = X + (size_t)(t0 + q15) * EMB + h * HD + g * 8;
        bf16x8 a0 = load8_cvt(xr);
        bf16x8 a1 = load8_cvt(xr + 32);
        f32x4 acc[4];
        #pragma unroll
        for (int nt = 0; nt < 4; ++nt) acc[nt] = (f32x4){0.f, 0.f, 0.f, 0.f};
        #pragma unroll
        for (int nt = 0; nt < 4; ++nt) {
            const float* wr = W + (nt * 16 + q15) * HD + g * 8;
            bf16x8 b0 = load8_cvt(wr);
            bf16x8 b1 = load8_cvt(wr + 32);
            acc[nt] = MFMA16(a0, b0, acc[nt]);
            acc[nt] = MFMA16(a1, b1, acc[nt]);
        }
        #pragma unroll
        for (int nt = 0; nt < 4; ++nt)
            #pragma unroll
            for (int r = 0; r < 4; ++r)
                O[(size_t)(s0 + g * 4 + r) * HD + nt * 16 + q15] = (bf16_t)(acc[nt][r] * scl);
    } else {
        const float* xr = values + (size_t)(t0 + q15) * EMB + h * HD + g * 8;
        bf16x8 b0 = load8_cvt(xr);
        bf16x8 b1 = load8_cvt(xr + 32);
        bf16_t* O = VpT + (size_t)(n * HEADS + h) * HD * S_LEN;
        f32x4 acc[4];
        #pragma unroll
        for (int et = 0; et < 4; ++et) acc[et] = (f32x4){0.f, 0.f, 0.f, 0.f};
        #pragma unroll
        for (int et = 0; et < 4; ++et) {
            const float* wr = Wv + (et * 16 + q15) * HD + g * 8;
            bf16x8 a0 = load8_cvt(wr);
            bf16x8 a1 = load8_cvt(wr + 32);
            acc[et] = MFMA16(a0, b0, acc[et]);
            acc[et] = MFMA16(a1, b1, acc[et]);
        }
        #pragma unroll
        for (int et = 0; et < 4; ++et)
            #pragma unroll
            for (int r = 0; r < 4; ++r)
                O[(size_t)(et * 16 + g * 4 + r) * S_LEN + s0 + q15] = (bf16_t)acc[et][r];
    }
}

// --------------------------------------------------------------------------
// Kernel 2: flash attention, templated on KV-split.
// SPLIT=1: grid 1024, writes normalized AO[n][s][h][d].
// SPLIT=2: grid 2048 (bid>>10 = half), writes unnormalized bf16 partials +
//          per-q (m, l) f32; merge_kernel combines.
// Swapped QK^T (S^T = K·Q^T): q = lane&15, softmax reduce = 2 shfl_xor.
// Q pre-scaled to log2 domain; defer-max skips acc rescale in common path;
// uniform branch skips masking when ballot is all-ones.
// --------------------------------------------------------------------------
template<int SPLIT>
__global__ __launch_bounds__(256) void attn_kernel(
    const bf16_t* __restrict__ Qp, const bf16_t* __restrict__ Kp,
    const bf16_t* __restrict__ VpT, const int* __restrict__ mask,
    bf16_t* __restrict__ Out, float2* __restrict__ Ml)
{
    __shared__ bf16_t plds[4][16][72];
    const int tid = threadIdx.x;
    const int w = tid >> 6, l = tid & 63, g = l >> 4, q15 = l & 15;
    const int bid = blockIdx.x;
    const int half = bid >> 10;
    const int rem = bid & 1023;
    const int nh = rem & 31, qt = rem >> 5;
    const int n = nh >> 4, h = nh & 15;
    const size_t hb = (size_t)nh * S_LEN * HD;
    const int qb = qt * 64 + w * 16;
    constexpr int TILES = 32 / SPLIT;

    const bf16_t* qr = Qp + hb + (size_t)(qb + q15) * HD + g * 8;
    const bf16x8 qf0 = *(const bf16x8*)(qr);
    const bf16x8 qf1 = *(const bf16x8*)(qr + 32);

    const int* __restrict__ mrow = mask + n * S_LEN;
    const bf16_t* __restrict__ kbase = Kp + hb;
    const bf16_t* __restrict__ vbase = VpT + hb;

    f32x4 acc[4];
    #pragma unroll
    for (int i = 0; i < 4; ++i) acc[i] = (f32x4){0.f, 0.f, 0.f, 0.f};
    float m_run = -INFINITY, l_run = 0.0f;
    bf16_t* prow = &plds[w][q15][0];

    for (int kt = half * TILES; kt < half * TILES + TILES; ++kt) {
        const int kb = kt * 64;
        const unsigned long long mb = __ballot(mrow[kb + l] != 0);

        // S^T[k][q] = K · Q^T
        f32x4 s[4];
        #pragma unroll
        for (int i = 0; i < 4; ++i) s[i] = (f32x4){0.f, 0.f, 0.f, 0.f};
        #pragma unroll
        for (int sub = 0; sub < 4; ++sub) {
            const bf16_t* kp = kbase + (size_t)(kb + sub * 16 + q15) * HD + g * 8;
            s[sub] = MFMA16(*(const bf16x8*)(kp), qf0, s[sub]);
            s[sub] = MFMA16(*(const bf16x8*)(kp + 32), qf1, s[sub]);
        }

        // prefetch V B-fragments (independent of softmax)
        bf16x8 vf[2][4];
        #pragma unroll
        for (int c = 0; c < 2; ++c)
            #pragma unroll
            for (int ds = 0; ds < 4; ++ds)
                vf[c][ds] = *(const bf16x8*)(vbase + (size_t)(ds * 16 + q15) * S_LEN
                                             + kb + 32 * c + g * 8);

        // masking only when some bit is off (uniform branch; mask is all-ones here)
        if (mb != ~0ull) {
            #pragma unroll
            for (int sub = 0; sub < 4; ++sub)
                #pragma unroll
                for (int r = 0; r < 4; ++r) {
                    const int j = sub * 16 + g * 4 + r;
                    if (!((mb >> j) & 1ull)) s[sub][r] = NEG_L2;
                }
        }

        // tile max (per q = q15, reduced across g)
        float pm = -INFINITY;
        #pragma unroll
        for (int sub = 0; sub < 4; ++sub)
            #pragma unroll
            for (int r = 0; r < 4; ++r) pm = fmaxf(pm, s[sub][r]);
        pm = fmaxf(pm, __shfl_xor(pm, 16));
        pm = fmaxf(pm, __shfl_xor(pm, 32));

        // defer-max: rescale only on significant growth (rare)
        if (!__all(pm <= m_run + DEFER_THR)) {
            const float mnew = fmaxf(m_run, pm);
            const float corr = exp2f(m_run - mnew);
            l_run *= corr;
            float cr[4];
            #pragma unroll
            for (int r = 0; r < 4; ++r) cr[r] = __shfl(corr, g * 4 + r);
            #pragma unroll
            for (int ds = 0; ds < 4; ++ds)
                #pragma unroll
                for (int r = 0; r < 4; ++r) acc[ds][r] *= cr[r];
            m_run = mnew;
        }

        // P = exp2(s - m), accumulate l, stage P rows to per-wave LDS
        float tsum = 0.0f;
        #pragma unroll
        for (int sub = 0; sub < 4; ++sub) {
            bf16x4 pk;
            #pragma unroll
            for (int r = 0; r < 4; ++r) {
                const float p = exp2f(s[sub][r] - m_run);
                tsum += p;
                pk[r] = (bf16_t)p;
            }
            *(bf16x4*)&prow[sub * 16 + g * 4] = pk;
        }
        tsum += __shfl_xor(tsum, 16);
        tsum += __shfl_xor(tsum, 32);
        l_run += tsum;

        asm volatile("" ::: "memory");  // order P writes before P reads

        // O[q][d] += P[q][k] · V[k][d]
        #pragma unroll
        for (int c = 0; c < 2; ++c) {
            const bf16x4 plo = *(const bf16x4*)&prow[32 * c + g * 8];
            const bf16x4 phi = *(const bf16x4*)&prow[32 * c + g * 8 + 4];
            bf16x8 pf;
            #pragma unroll
            for (int i = 0; i < 4; ++i) { pf[i] = plo[i]; pf[i + 4] = phi[i]; }
            #pragma unroll
            for (int ds = 0; ds < 4; ++ds)
                acc[ds] = MFMA16(pf, vf[c][ds], acc[ds]);
        }
        asm volatile("" ::: "memory");  // P reads before next-iter writes
    }

    if (SPLIT == 1) {
        // normalize and write AO[n][s][h][d] via per-wave LDS transpose
        float li[4];
        #pragma unroll
        for (int r = 0; r < 4; ++r) li[r] = 1.0f / __shfl(l_run, g * 4 + r);
        #pragma unroll
        for (int ds = 0; ds < 4; ++ds)
            #pragma unroll
            for (int r = 0; r < 4; ++r)
                plds[w][g * 4 + r][ds * 16 + q15] = (bf16_t)(acc[ds][r] * li[r]);
        asm volatile("" ::: "memory");
        const int qrow = l >> 2, seg = (l & 3) * 16;
        const bf16x8 o0 = *(const bf16x8*)&plds[w][qrow][seg];
        const bf16x8 o1 = *(const bf16x8*)&plds[w][qrow][seg + 8];
        bf16_t* op = Out + (size_t)(n * S_LEN + qb + qrow) * EMB + h * HD + seg;
        *(bf16x8*)(op) = o0;
        *(bf16x8*)(op + 8) = o1;
    } else {
        // unnormalized partial + (m, l)
        #pragma unroll
        for (int ds = 0; ds < 4; ++ds)
            #pragma unroll
            for (int r = 0; r < 4; ++r)
                plds[w][g * 4 + r][ds * 16 + q15] = (bf16_t)acc[ds][r];
        asm volatile("" ::: "memory");
        const int qrow = l >> 2, seg = (l & 3) * 16;
        const bf16x8 o0 = *(const bf16x8*)&plds[w][qrow][seg];
        const bf16x8 o1 = *(const bf16x8*)&plds[w][qrow][seg + 8];
        bf16_t* op = Out + ((size_t)(half * 32 + nh) * S_LEN + qb + qrow) * HD + seg;
        *(bf16x8*)(op) = o0;
        *(bf16x8*)(op + 8) = o1;
        if (l < 16)
            Ml[(half << 16) + nh * S_LEN + qb + l] = make_float2(m_run, l_run);
    }
}

// --------------------------------------------------------------------------
// Kernel 2b: merge two KV-split partials. grid 1024 x 256.
// gid -> (gq = nh*2048+s, seg of 16 d elems).
// --------------------------------------------------------------------------
__global__ __launch_bounds__(256) void merge_kernel(
    const bf16_t* __restrict__ Opart, const float2* __restrict__ Ml,
    bf16_t* __restrict__ AO)
{
    const int gid = blockIdx.x * 256 + threadIdx.x;
    const int gq = gid >> 2, seg = (gid & 3) * 16;
    const int nh = gq >> 11, s = gq & 2047;
    const int n = nh >> 4, h = nh & 15;
    const float2 ml0 = Ml[gq];
    const float2 ml1 = Ml[65536 + gq];
    const float m = fmaxf(ml0.x, ml1.x);
    const float w0 = exp2f(ml0.x - m);
    const float w1 = exp2f(ml1.x - m);
    const float inv = 1.0f / (w0 * ml0.y + w1 * ml1.y);
    const bf16_t* p0 = Opart + (size_t)gq * HD + seg;
    const bf16_t* p1 = p0 + (size_t)32 * S_LEN * HD;
    const bf16x8 a0 = *(const bf16x8*)(p0);
    const bf16x8 a1 = *(const bf16x8*)(p0 + 8);
    const bf16x8 b0 = *(const bf16x8*)(p1);
    const bf16x8 b1 = *(const bf16x8*)(p1 + 8);
    bf16x8 r0, r1;
    #pragma unroll
    for (int j = 0; j < 8; ++j) {
        r0[j] = (bf16_t)((w0 * (float)a0[j] + w1 * (float)b0[j]) * inv);
        r1[j] = (bf16_t)((w0 * (float)a1[j] + w1 * (float)b1[j]) * inv);
    }
    bf16_t* op = AO + (size_t)(n * S_LEN + s) * EMB + h * HD + seg;
    *(bf16x8*)(op) = r0;
    *(bf16x8*)(op + 8) = r1;
}

// --------------------------------------------------------------------------
// Kernel 3: out = AO @ Wo^T + bo.  M=4096, N=1024, K=1024. fp32 out.
// 128x64 tile (512 blocks, 2/CU), BK=64, 4 waves (2x2, each 64x32).
// --------------------------------------------------------------------------
__global__ __launch_bounds__(256) void outproj_kernel(
    const bf16_t* __restrict__ X, const float* __restrict__ Wo,
    const float* __restrict__ bo, float* __restrict__ out)
{
    __shared__ bf16_t Xs[128 * 64];
    __shared__ bf16_t Ws[64 * 64];
    const int tid = threadIdx.x;
    const int w = tid >> 6, l = tid & 63, g = l >> 4, q15 = l & 15;
    const int m0 = (blockIdx.x >> 4) * 128;
    const int n0 = (blockIdx.x & 15) * 64;
    const int wm = (w >> 1) * 64, wn = (w & 1) * 32;

    f32x4 acc[4][2];
    #pragma unroll
    for (int i = 0; i < 4; ++i)
        #pragma unroll
        for (int j = 0; j < 2; ++j) acc[i][j] = (f32x4){0.f, 0.f, 0.f, 0.f};

    for (int k0 = 0; k0 < EMB; k0 += 64) {
        __syncthreads();
        #pragma unroll
        for (int j = 0; j < 4; ++j) {
            const int cid = tid + 256 * j;
            const int r = cid >> 3, pc = cid & 7;
            const int sw = (pc ^ (r & 7)) * 8;
            *(bf16x8*)&Xs[r * 64 + sw] =
                *(const bf16x8*)(X + (size_t)(m0 + r) * EMB + k0 + pc * 8);
        }
        #pragma unroll
        for (int j = 0; j < 2; ++j) {
            const int cid = tid + 256 * j;
            const int r = cid >> 3, pc = cid & 7;
            const int sw = (pc ^ (r & 7)) * 8;
            *(bf16x8*)&Ws[r * 64 + sw] =
                load8_cvt(Wo + (size_t)(n0 + r) * EMB + k0 + pc * 8);
        }
        __syncthreads();
        #pragma unroll
        for (int c = 0; c < 2; ++c) {
            bf16x8 av[4], bv[2];
            #pragma unroll
            for (int mt = 0; mt < 4; ++mt) {
                const int r = wm + mt * 16 + q15;
                av[mt] = *(const bf16x8*)&Xs[r * 64 + (((4 * c + g) ^ (r & 7)) * 8)];
            }
            #pragma unroll
            for (int nt = 0; nt < 2; ++nt) {
                const int r = wn + nt * 16 + q15;
                bv[nt] = *(const bf16x8*)&Ws[r * 64 + (((4 * c + g) ^ (r & 7)) * 8)];
            }
            #pragma unroll
            for (int mt = 0; mt < 4; ++mt)
                #pragma unroll
                for (int nt = 0; nt < 2; ++nt)
                    acc[mt][nt] = MFMA16(av[mt], bv[nt], acc[mt][nt]);
        }
    }

    float bias[2];
    #pragma unroll
    for (int nt = 0; nt < 2; ++nt) bias[nt] = bo[n0 + wn + nt * 16 + q15];
    #pragma unroll
    for (int mt = 0; mt < 4; ++mt)
        #pragma unroll
        for (int nt = 0; nt < 2; ++nt)
            #pragma unroll
            for (int r = 0; r < 4; ++r)
                out[(size_t)(m0 + wm + mt * 16 + g * 4 + r) * EMB + n0 + wn + nt * 16 + q15]
                    = acc[mt][nt][r] + bias[nt];
}

// --------------------------------------------------------------------------
extern "C" void kernel_launch(void* const* d_in, const int* in_sizes, int n_in,
                              void* d_out, int out_size, void* d_ws, size_t ws_size,
                              hipStream_t stream) {
    const float* values  = (const float*)d_in[0];
    const float* keys    = (const float*)d_in[1];
    const float* queries = (const float*)d_in[2];
    const int*   mask    = (const int*)d_in[3];
    const float* Wv      = (const float*)d_in[4];
    const float* Wk      = (const float*)d_in[5];
    const float* Wq      = (const float*)d_in[6];
    const float* Wo      = (const float*)d_in[7];
    const float* bo      = (const float*)d_in[8];
    float* out = (float*)d_out;

    // ws layout (bf16 elems): Qp[0,4M) Kp[4M,8M) VpT[8M,12M) AO[12M,16M)
    // split-2 extras: Opart[16M,24M) elems, Ml at byte 48MB (1MB) -> 49MB total
    bf16_t* Qp    = (bf16_t*)d_ws;
    bf16_t* Kp    = Qp  + (size_t)4194304;
    bf16_t* VpT   = Kp  + (size_t)4194304;
    bf16_t* AO    = VpT + (size_t)4194304;
    bf16_t* Opart = AO  + (size_t)4194304;
    float2* Ml    = (float2*)((char*)d_ws + (size_t)48 * 1024 * 1024);

    proj_kernel<<<3072, 256, 0, stream>>>(values, keys, queries, Wv, Wk, Wq, Qp, Kp, VpT);

    const bool split2 = ws_size >= (size_t)50 * 1024 * 1024;
    if (split2) {
        attn_kernel<2><<<2048, 256, 0, stream>>>(Qp, Kp, VpT, mask, Opart, Ml);
        merge_kernel<<<1024, 256, 0, stream>>>(Opart, Ml, AO);
    } else {
        attn_kernel<1><<<1024, 256, 0, stream>>>(Qp, Kp, VpT, mask, AO, nullptr);
    }

    outproj_kernel<<<512, 256, 0, stream>>>(AO, Wo, bo, out);
}

// Round 4
// 179.245 us; speedup vs baseline: 1.7724x; 1.7724x over previous
//
#include <hip/hip_runtime.h>

typedef __bf16 bf16_t;
typedef __bf16 bf16x8 __attribute__((ext_vector_type(8)));
typedef __bf16 bf16x4 __attribute__((ext_vector_type(4)));
typedef float f32x4 __attribute__((ext_vector_type(4)));

#define MFMA16(a, b, c) __builtin_amdgcn_mfma_f32_16x16x32_bf16((a), (b), (c), 0, 0, 0)

namespace {
constexpr int S_LEN = 2048;
constexpr int EMB   = 1024;
constexpr int HEADS = 16;
constexpr int HD    = 64;
// Q pre-scaled by log2(e)/sqrt(EMB): scores are in the log2 domain.
constexpr float Q_PRESCALE = 1.44269504088896340736f / 32.0f;
constexpr float NEG_L2     = -4.5084e18f;   // -1e20 * log2(e)/32
constexpr float DEFER_THR  = 8.0f;          // skip rescale if growth <= 8 (p <= 256)
}

// load 8 contiguous fp32 and round to bf16x8
__device__ __forceinline__ bf16x8 load8_cvt(const float* __restrict__ p) {
    const f32x4 a = *(const f32x4*)p;
    const f32x4 b = *(const f32x4*)(p + 4);
    bf16x8 r;
    r[0] = (bf16_t)a[0]; r[1] = (bf16_t)a[1]; r[2] = (bf16_t)a[2]; r[3] = (bf16_t)a[3];
    r[4] = (bf16_t)b[0]; r[5] = (bf16_t)b[1]; r[6] = (bf16_t)b[2]; r[7] = (bf16_t)b[3];
    return r;
}

// --------------------------------------------------------------------------
// Kernel 1: per-head projections (fp32 in -> bf16 out).
//   mat 0: Qp[nh][s][d]  = (queries @ Wq^T) * Q_PRESCALE
//   mat 1: Kp[nh][s][d]  = keys @ Wk^T
//   mat 2: VpT[nh][d][s] = (values @ Wv^T)^T
// --------------------------------------------------------------------------
__global__ __launch_bounds__(256) void proj_kernel(
    const float* __restrict__ values, const float* __restrict__ keys,
    const float* __restrict__ queries,
    const float* __restrict__ Wv, const float* __restrict__ Wk,
    const float* __restrict__ Wq,
    bf16_t* __restrict__ Qp, bf16_t* __restrict__ Kp, bf16_t* __restrict__ VpT)
{
    const int tid = threadIdx.x;
    const int w = tid >> 6, l = tid & 63, g = l >> 4, q15 = l & 15;
    const int b   = blockIdx.x;
    const int mat = b >> 10;          // 0=Q, 1=K, 2=V
    const int rem = b & 1023;
    const int h   = rem >> 6;
    const int t0  = (((rem & 63) << 2) + w) << 4;
    const int n   = t0 >> 11;
    const int s0  = t0 & 2047;

    if (mat < 2) {
        const float* X = (mat == 0) ? queries : keys;
        const float* W = (mat == 0) ? Wq : Wk;
        const float scl = (mat == 0) ? Q_PRESCALE : 1.0f;
        bf16_t* O = ((mat == 0) ? Qp : Kp) + (size_t)(n * HEADS + h) * S_LEN * HD;
        const float* xr = X + (size_t)(t0 + q15) * EMB + h * HD + g * 8;
        bf16x8 a0 = load8_cvt(xr);
        bf16x8 a1 = load8_cvt(xr + 32);
        f32x4 acc[4];
        #pragma unroll
        for (int nt = 0; nt < 4; ++nt) acc[nt] = (f32x4){0.f, 0.f, 0.f, 0.f};
        #pragma unroll
        for (int nt = 0; nt < 4; ++nt) {
            const float* wr = W + (nt * 16 + q15) * HD + g * 8;
            bf16x8 b0 = load8_cvt(wr);
            bf16x8 b1 = load8_cvt(wr + 32);
            acc[nt] = MFMA16(a0, b0, acc[nt]);
            acc[nt] = MFMA16(a1, b1, acc[nt]);
        }
        #pragma unroll
        for (int nt = 0; nt < 4; ++nt)
            #pragma unroll
            for (int r = 0; r < 4; ++r)
                O[(size_t)(s0 + g * 4 + r) * HD + nt * 16 + q15] = (bf16_t)(acc[nt][r] * scl);
    } else {
        const float* xr = values + (size_t)(t0 + q15) * EMB + h * HD + g * 8;
        bf16x8 b0 = load8_cvt(xr);
        bf16x8 b1 = load8_cvt(xr + 32);
        bf16_t* O = VpT + (size_t)(n * HEADS + h) * HD * S_LEN;
        f32x4 acc[4];
        #pragma unroll
        for (int et = 0; et < 4; ++et) acc[et] = (f32x4){0.f, 0.f, 0.f, 0.f};
        #pragma unroll
        for (int et = 0; et < 4; ++et) {
            const float* wr = Wv + (et * 16 + q15) * HD + g * 8;
            bf16x8 a0 = load8_cvt(wr);
            bf16x8 a1 = load8_cvt(wr + 32);
            acc[et] = MFMA16(a0, b0, acc[et]);
            acc[et] = MFMA16(a1, b1, acc[et]);
        }
        #pragma unroll
        for (int et = 0; et < 4; ++et)
            #pragma unroll
            for (int r = 0; r < 4; ++r)
                O[(size_t)(et * 16 + g * 4 + r) * S_LEN + s0 + q15] = (bf16_t)acc[et][r];
    }
}

// --------------------------------------------------------------------------
// Kernel 2: flash attention, 32 q-rows per wave (two independent 16-row
// sets A/B sharing K and V fragment loads). grid = 512 (bid = qt*32 + nh;
// same-head blocks land on one XCD). Swapped QK^T: q = lane&15, softmax
// reduce = 2 shfl_xor per set; the A/B chains interleave for ILP.
// --------------------------------------------------------------------------
__global__ __launch_bounds__(256, 2) void attn_kernel(
    const bf16_t* __restrict__ Qp, const bf16_t* __restrict__ Kp,
    const bf16_t* __restrict__ VpT, const int* __restrict__ mask,
    bf16_t* __restrict__ AO)
{
    __shared__ bf16_t plds[4][32][72];   // per-wave P rows (A: 0-15, B: 16-31)
    const int tid = threadIdx.x;
    const int w = tid >> 6, l = tid & 63, g = l >> 4, q15 = l & 15;
    const int bid = blockIdx.x;
    const int nh = bid & 31, qt = bid >> 5;   // qt in [0,16)
    const int n = nh >> 4, h = nh & 15;
    const size_t hb = (size_t)nh * S_LEN * HD;
    const int qb = qt * 128 + w * 32;

    // Q B-fragments for both 16-row sets (col = q = lane&15, k = d)
    const bf16_t* qrA = Qp + hb + (size_t)(qb + q15) * HD + g * 8;
    const bf16_t* qrB = qrA + 16 * HD;
    const bf16x8 qfA0 = *(const bf16x8*)(qrA);
    const bf16x8 qfA1 = *(const bf16x8*)(qrA + 32);
    const bf16x8 qfB0 = *(const bf16x8*)(qrB);
    const bf16x8 qfB1 = *(const bf16x8*)(qrB + 32);

    const int* __restrict__ mrow = mask + n * S_LEN;
    const bf16_t* __restrict__ kbase = Kp + hb;
    const bf16_t* __restrict__ vbase = VpT + hb;

    f32x4 accA[4], accB[4];
    #pragma unroll
    for (int i = 0; i < 4; ++i) {
        accA[i] = (f32x4){0.f, 0.f, 0.f, 0.f};
        accB[i] = (f32x4){0.f, 0.f, 0.f, 0.f};
    }
    float mA = -INFINITY, lA = 0.0f;
    float mB = -INFINITY, lB = 0.0f;
    bf16_t* prowA = &plds[w][q15][0];
    bf16_t* prowB = &plds[w][16 + q15][0];

    for (int kt = 0; kt < 32; ++kt) {
        const int kb = kt * 64;
        const unsigned long long mb = __ballot(mrow[kb + l] != 0);

        // S^T = K · Q^T for both q-sets, sharing each K fragment load
        f32x4 sA[4], sB[4];
        #pragma unroll
        for (int i = 0; i < 4; ++i) {
            sA[i] = (f32x4){0.f, 0.f, 0.f, 0.f};
            sB[i] = (f32x4){0.f, 0.f, 0.f, 0.f};
        }
        #pragma unroll
        for (int sub = 0; sub < 4; ++sub) {
            const bf16_t* kp = kbase + (size_t)(kb + sub * 16 + q15) * HD + g * 8;
            const bf16x8 k0 = *(const bf16x8*)(kp);
            const bf16x8 k1 = *(const bf16x8*)(kp + 32);
            sA[sub] = MFMA16(k0, qfA0, sA[sub]);
            sA[sub] = MFMA16(k1, qfA1, sA[sub]);
            sB[sub] = MFMA16(k0, qfB0, sB[sub]);
            sB[sub] = MFMA16(k1, qfB1, sB[sub]);
        }

        // V fragments (shared by both sets), issued before softmax
        bf16x8 vf[2][4];
        #pragma unroll
        for (int c = 0; c < 2; ++c)
            #pragma unroll
            for (int ds = 0; ds < 4; ++ds)
                vf[c][ds] = *(const bf16x8*)(vbase + (size_t)(ds * 16 + q15) * S_LEN
                                             + kb + 32 * c + g * 8);

        // masking only when some bit is off (uniform branch)
        if (mb != ~0ull) {
            #pragma unroll
            for (int sub = 0; sub < 4; ++sub)
                #pragma unroll
                for (int r = 0; r < 4; ++r) {
                    const int j = sub * 16 + g * 4 + r;
                    if (!((mb >> j) & 1ull)) { sA[sub][r] = NEG_L2; sB[sub][r] = NEG_L2; }
                }
        }

        // --- softmax, two independent chains (ILP) ---
        float pmA = -INFINITY, pmB = -INFINITY;
        #pragma unroll
        for (int sub = 0; sub < 4; ++sub)
            #pragma unroll
            for (int r = 0; r < 4; ++r) {
                pmA = fmaxf(pmA, sA[sub][r]);
                pmB = fmaxf(pmB, sB[sub][r]);
            }
        pmA = fmaxf(pmA, __shfl_xor(pmA, 16));
        pmB = fmaxf(pmB, __shfl_xor(pmB, 16));
        pmA = fmaxf(pmA, __shfl_xor(pmA, 32));
        pmB = fmaxf(pmB, __shfl_xor(pmB, 32));

        if (!__all(pmA <= mA + DEFER_THR)) {
            const float mnew = fmaxf(mA, pmA);
            const float corr = exp2f(mA - mnew);
            lA *= corr;
            float cr[4];
            #pragma unroll
            for (int r = 0; r < 4; ++r) cr[r] = __shfl(corr, g * 4 + r);
            #pragma unroll
            for (int ds = 0; ds < 4; ++ds)
                #pragma unroll
                for (int r = 0; r < 4; ++r) accA[ds][r] *= cr[r];
            mA = mnew;
        }
        if (!__all(pmB <= mB + DEFER_THR)) {
            const float mnew = fmaxf(mB, pmB);
            const float corr = exp2f(mB - mnew);
            lB *= corr;
            float cr[4];
            #pragma unroll
            for (int r = 0; r < 4; ++r) cr[r] = __shfl(corr, g * 4 + r);
            #pragma unroll
            for (int ds = 0; ds < 4; ++ds)
                #pragma unroll
                for (int r = 0; r < 4; ++r) accB[ds][r] *= cr[r];
            mB = mnew;
        }

        float tsA = 0.0f, tsB = 0.0f;
        #pragma unroll
        for (int sub = 0; sub < 4; ++sub) {
            bf16x4 pkA, pkB;
            #pragma unroll
            for (int r = 0; r < 4; ++r) {
                const float pa = exp2f(sA[sub][r] - mA);
                const float pb = exp2f(sB[sub][r] - mB);
                tsA += pa; tsB += pb;
                pkA[r] = (bf16_t)pa; pkB[r] = (bf16_t)pb;
            }
            *(bf16x4*)&prowA[sub * 16 + g * 4] = pkA;
            *(bf16x4*)&prowB[sub * 16 + g * 4] = pkB;
        }
        tsA += __shfl_xor(tsA, 16); tsB += __shfl_xor(tsB, 16);
        tsA += __shfl_xor(tsA, 32); tsB += __shfl_xor(tsB, 32);
        lA += tsA; lB += tsB;

        asm volatile("" ::: "memory");  // order P writes before P reads

        // O += P · V, both sets sharing vf
        #pragma unroll
        for (int c = 0; c < 2; ++c) {
            const bf16x4 aLo = *(const bf16x4*)&prowA[32 * c + g * 8];
            const bf16x4 aHi = *(const bf16x4*)&prowA[32 * c + g * 8 + 4];
            const bf16x4 bLo = *(const bf16x4*)&prowB[32 * c + g * 8];
            const bf16x4 bHi = *(const bf16x4*)&prowB[32 * c + g * 8 + 4];
            bf16x8 pfA, pfB;
            #pragma unroll
            for (int i = 0; i < 4; ++i) {
                pfA[i] = aLo[i]; pfA[i + 4] = aHi[i];
                pfB[i] = bLo[i]; pfB[i + 4] = bHi[i];
            }
            #pragma unroll
            for (int ds = 0; ds < 4; ++ds) {
                accA[ds] = MFMA16(pfA, vf[c][ds], accA[ds]);
                accB[ds] = MFMA16(pfB, vf[c][ds], accB[ds]);
            }
        }
        asm volatile("" ::: "memory");  // P reads before next-iter writes
    }

    // normalize and write AO[n][s][h][d] via per-wave LDS transpose
    float liA[4], liB[4];
    #pragma unroll
    for (int r = 0; r < 4; ++r) {
        liA[r] = 1.0f / __shfl(lA, g * 4 + r);
        liB[r] = 1.0f / __shfl(lB, g * 4 + r);
    }
    #pragma unroll
    for (int ds = 0; ds < 4; ++ds)
        #pragma unroll
        for (int r = 0; r < 4; ++r) {
            plds[w][g * 4 + r][ds * 16 + q15]      = (bf16_t)(accA[ds][r] * liA[r]);
            plds[w][16 + g * 4 + r][ds * 16 + q15] = (bf16_t)(accB[ds][r] * liB[r]);
        }
    asm volatile("" ::: "memory");

    const int qrow = l >> 2, seg = (l & 3) * 16;
    #pragma unroll
    for (int set = 0; set < 2; ++set) {
        const bf16x8 o0 = *(const bf16x8*)&plds[w][set * 16 + qrow][seg];
        const bf16x8 o1 = *(const bf16x8*)&plds[w][set * 16 + qrow][seg + 8];
        bf16_t* op = AO + (size_t)(n * S_LEN + qb + set * 16 + qrow) * EMB + h * HD + seg;
        *(bf16x8*)(op) = o0;
        *(bf16x8*)(op + 8) = o1;
    }
}

// --------------------------------------------------------------------------
// Kernel 3: out = AO @ Wo^T + bo.  M=4096, N=1024, K=1024. fp32 out.
// 128x64 tile (512 blocks), BK=64, 4 waves (2x2, each 64x32).
// --------------------------------------------------------------------------
__global__ __launch_bounds__(256) void outproj_kernel(
    const bf16_t* __restrict__ X, const float* __restrict__ Wo,
    const float* __restrict__ bo, float* __restrict__ out)
{
    __shared__ bf16_t Xs[128 * 64];
    __shared__ bf16_t Ws[64 * 64];
    const int tid = threadIdx.x;
    const int w = tid >> 6, l = tid & 63, g = l >> 4, q15 = l & 15;
    const int m0 = (blockIdx.x >> 4) * 128;
    const int n0 = (blockIdx.x & 15) * 64;
    const int wm = (w >> 1) * 64, wn = (w & 1) * 32;

    f32x4 acc[4][2];
    #pragma unroll
    for (int i = 0; i < 4; ++i)
        #pragma unroll
        for (int j = 0; j < 2; ++j) acc[i][j] = (f32x4){0.f, 0.f, 0.f, 0.f};

    for (int k0 = 0; k0 < EMB; k0 += 64) {
        __syncthreads();
        #pragma unroll
        for (int j = 0; j < 4; ++j) {
            const int cid = tid + 256 * j;
            const int r = cid >> 3, pc = cid & 7;
            const int sw = (pc ^ (r & 7)) * 8;
            *(bf16x8*)&Xs[r * 64 + sw] =
                *(const bf16x8*)(X + (size_t)(m0 + r) * EMB + k0 + pc * 8);
        }
        #pragma unroll
        for (int j = 0; j < 2; ++j) {
            const int cid = tid + 256 * j;
            const int r = cid >> 3, pc = cid & 7;
            const int sw = (pc ^ (r & 7)) * 8;
            *(bf16x8*)&Ws[r * 64 + sw] =
                load8_cvt(Wo + (size_t)(n0 + r) * EMB + k0 + pc * 8);
        }
        __syncthreads();
        #pragma unroll
        for (int c = 0; c < 2; ++c) {
            bf16x8 av[4], bv[2];
            #pragma unroll
            for (int mt = 0; mt < 4; ++mt) {
                const int r = wm + mt * 16 + q15;
                av[mt] = *(const bf16x8*)&Xs[r * 64 + (((4 * c + g) ^ (r & 7)) * 8)];
            }
            #pragma unroll
            for (int nt = 0; nt < 2; ++nt) {
                const int r = wn + nt * 16 + q15;
                bv[nt] = *(const bf16x8*)&Ws[r * 64 + (((4 * c + g) ^ (r & 7)) * 8)];
            }
            #pragma unroll
            for (int mt = 0; mt < 4; ++mt)
                #pragma unroll
                for (int nt = 0; nt < 2; ++nt)
                    acc[mt][nt] = MFMA16(av[mt], bv[nt], acc[mt][nt]);
        }
    }

    float bias[2];
    #pragma unroll
    for (int nt = 0; nt < 2; ++nt) bias[nt] = bo[n0 + wn + nt * 16 + q15];
    #pragma unroll
    for (int mt = 0; mt < 4; ++mt)
        #pragma unroll
        for (int nt = 0; nt < 2; ++nt)
            #pragma unroll
            for (int r = 0; r < 4; ++r)
                out[(size_t)(m0 + wm + mt * 16 + g * 4 + r) * EMB + n0 + wn + nt * 16 + q15]
                    = acc[mt][nt][r] + bias[nt];
}

// --------------------------------------------------------------------------
extern "C" void kernel_launch(void* const* d_in, const int* in_sizes, int n_in,
                              void* d_out, int out_size, void* d_ws, size_t ws_size,
                              hipStream_t stream) {
    const float* values  = (const float*)d_in[0];
    const float* keys    = (const float*)d_in[1];
    const float* queries = (const float*)d_in[2];
    const int*   mask    = (const int*)d_in[3];
    const float* Wv      = (const float*)d_in[4];
    const float* Wk      = (const float*)d_in[5];
    const float* Wq      = (const float*)d_in[6];
    const float* Wo      = (const float*)d_in[7];
    const float* bo      = (const float*)d_in[8];
    float* out = (float*)d_out;

    // ws layout (bf16 elems): Qp[0,4M) Kp[4M,8M) VpT[8M,12M) AO[12M,16M)
    bf16_t* Qp  = (bf16_t*)d_ws;
    bf16_t* Kp  = Qp  + (size_t)4194304;
    bf16_t* VpT = Kp  + (size_t)4194304;
    bf16_t* AO  = VpT + (size_t)4194304;

    proj_kernel<<<3072, 256, 0, stream>>>(values, keys, queries, Wv, Wk, Wq, Qp, Kp, VpT);
    attn_kernel<<<512, 256, 0, stream>>>(Qp, Kp, VpT, mask, AO);
    outproj_kernel<<<512, 256, 0, stream>>>(AO, Wo, bo, out);
}

// Round 5
// 176.101 us; speedup vs baseline: 1.8040x; 1.0179x over previous
//
#include <hip/hip_runtime.h>

typedef __bf16 bf16_t;
typedef __bf16 bf16x8 __attribute__((ext_vector_type(8)));
typedef __bf16 bf16x4 __attribute__((ext_vector_type(4)));
typedef float f32x4 __attribute__((ext_vector_type(4)));

#define MFMA16(a, b, c) __builtin_amdgcn_mfma_f32_16x16x32_bf16((a), (b), (c), 0, 0, 0)

namespace {
constexpr int S_LEN = 2048;
constexpr int EMB   = 1024;
constexpr int HEADS = 16;
constexpr int HD    = 64;
// Q pre-scaled by log2(e)/sqrt(EMB): scores are in the log2 domain.
constexpr float Q_PRESCALE = 1.44269504088896340736f / 32.0f;
constexpr float NEG_L2     = -4.5084e18f;   // -1e20 * log2(e)/32
constexpr float DEFER_THR  = 8.0f;          // skip rescale if growth <= 8 (p <= 256)
}

// load 8 contiguous fp32 and round to bf16x8
__device__ __forceinline__ bf16x8 load8_cvt(const float* __restrict__ p) {
    const f32x4 a = *(const f32x4*)p;
    const f32x4 b = *(const f32x4*)(p + 4);
    bf16x8 r;
    r[0] = (bf16_t)a[0]; r[1] = (bf16_t)a[1]; r[2] = (bf16_t)a[2]; r[3] = (bf16_t)a[3];
    r[4] = (bf16_t)b[0]; r[5] = (bf16_t)b[1]; r[6] = (bf16_t)b[2]; r[7] = (bf16_t)b[3];
    return r;
}

// --------------------------------------------------------------------------
// Kernel 1: per-head projections (fp32 in -> bf16 out).
//   mat 0: Qp[nh][s][d]  = (queries @ Wq^T) * Q_PRESCALE
//   mat 1: Kp[nh][s][d]  = keys @ Wk^T
//   mat 2: VpT[nh][d][s] = (values @ Wv^T)^T
// --------------------------------------------------------------------------
__global__ __launch_bounds__(256) void proj_kernel(
    const float* __restrict__ values, const float* __restrict__ keys,
    const float* __restrict__ queries,
    const float* __restrict__ Wv, const float* __restrict__ Wk,
    const float* __restrict__ Wq,
    bf16_t* __restrict__ Qp, bf16_t* __restrict__ Kp, bf16_t* __restrict__ VpT)
{
    const int tid = threadIdx.x;
    const int w = tid >> 6, l = tid & 63, g = l >> 4, q15 = l & 15;
    const int b   = blockIdx.x;
    const int mat = b >> 10;          // 0=Q, 1=K, 2=V
    const int rem = b & 1023;
    const int h   = rem >> 6;
    const int t0  = (((rem & 63) << 2) + w) << 4;
    const int n   = t0 >> 11;
    const int s0  = t0 & 2047;

    if (mat < 2) {
        const float* X = (mat == 0) ? queries : keys;
        const float* W = (mat == 0) ? Wq : Wk;
        const float scl = (mat == 0) ? Q_PRESCALE : 1.0f;
        bf16_t* O = ((mat == 0) ? Qp : Kp) + (size_t)(n * HEADS + h) * S_LEN * HD;
        const float* xr = X + (size_t)(t0 + q15) * EMB + h * HD + g * 8;
        bf16x8 a0 = load8_cvt(xr);
        bf16x8 a1 = load8_cvt(xr + 32);
        f32x4 acc[4];
        #pragma unroll
        for (int nt = 0; nt < 4; ++nt) acc[nt] = (f32x4){0.f, 0.f, 0.f, 0.f};
        #pragma unroll
        for (int nt = 0; nt < 4; ++nt) {
            const float* wr = W + (nt * 16 + q15) * HD + g * 8;
            bf16x8 b0 = load8_cvt(wr);
            bf16x8 b1 = load8_cvt(wr + 32);
            acc[nt] = MFMA16(a0, b0, acc[nt]);
            acc[nt] = MFMA16(a1, b1, acc[nt]);
        }
        #pragma unroll
        for (int nt = 0; nt < 4; ++nt)
            #pragma unroll
            for (int r = 0; r < 4; ++r)
                O[(size_t)(s0 + g * 4 + r) * HD + nt * 16 + q15] = (bf16_t)(acc[nt][r] * scl);
    } else {
        const float* xr = values + (size_t)(t0 + q15) * EMB + h * HD + g * 8;
        bf16x8 b0 = load8_cvt(xr);
        bf16x8 b1 = load8_cvt(xr + 32);
        bf16_t* O = VpT + (size_t)(n * HEADS + h) * HD * S_LEN;
        f32x4 acc[4];
        #pragma unroll
        for (int et = 0; et < 4; ++et) acc[et] = (f32x4){0.f, 0.f, 0.f, 0.f};
        #pragma unroll
        for (int et = 0; et < 4; ++et) {
            const float* wr = Wv + (et * 16 + q15) * HD + g * 8;
            bf16x8 a0 = load8_cvt(wr);
            bf16x8 a1 = load8_cvt(wr + 32);
            acc[et] = MFMA16(a0, b0, acc[et]);
            acc[et] = MFMA16(a1, b1, acc[et]);
        }
        #pragma unroll
        for (int et = 0; et < 4; ++et)
            #pragma unroll
            for (int r = 0; r < 4; ++r)
                O[(size_t)(et * 16 + g * 4 + r) * S_LEN + s0 + q15] = (bf16_t)acc[et][r];
    }
}

// --------------------------------------------------------------------------
// Kernel 2: flash attention, 32 q-rows per wave (two independent 16-row
// sets A/B sharing K and V fragment loads), K register-double-buffered
// across KV tiles (next tile's K loads issue right after current QK^T
// consumes the buffer -> ~1 tile body of latency cover). grid = 512.
// Swapped QK^T: q = lane&15, softmax reduce = 2 shfl_xor per set.
// --------------------------------------------------------------------------
__global__ __launch_bounds__(256, 2) void attn_kernel(
    const bf16_t* __restrict__ Qp, const bf16_t* __restrict__ Kp,
    const bf16_t* __restrict__ VpT, const int* __restrict__ mask,
    bf16_t* __restrict__ AO)
{
    __shared__ bf16_t plds[4][32][72];   // per-wave P rows (A: 0-15, B: 16-31)
    const int tid = threadIdx.x;
    const int w = tid >> 6, l = tid & 63, g = l >> 4, q15 = l & 15;
    const int bid = blockIdx.x;
    const int nh = bid & 31, qt = bid >> 5;   // qt in [0,16)
    const int n = nh >> 4, h = nh & 15;
    const size_t hb = (size_t)nh * S_LEN * HD;
    const int qb = qt * 128 + w * 32;

    // Q B-fragments for both 16-row sets (col = q = lane&15, k = d)
    const bf16_t* qrA = Qp + hb + (size_t)(qb + q15) * HD + g * 8;
    const bf16_t* qrB = qrA + 16 * HD;
    const bf16x8 qfA0 = *(const bf16x8*)(qrA);
    const bf16x8 qfA1 = *(const bf16x8*)(qrA + 32);
    const bf16x8 qfB0 = *(const bf16x8*)(qrB);
    const bf16x8 qfB1 = *(const bf16x8*)(qrB + 32);

    const int* __restrict__ mrow = mask + n * S_LEN;
    // per-lane K/V base pointers (per-tile addressing = base + immediate-ish)
    const bf16_t* kp0 = Kp  + hb + (size_t)q15 * HD + g * 8;
    const bf16_t* vp0 = VpT + hb + (size_t)q15 * S_LEN + g * 8;

    f32x4 accA[4], accB[4];
    #pragma unroll
    for (int i = 0; i < 4; ++i) {
        accA[i] = (f32x4){0.f, 0.f, 0.f, 0.f};
        accB[i] = (f32x4){0.f, 0.f, 0.f, 0.f};
    }
    float mA = -INFINITY, lA = 0.0f;
    float mB = -INFINITY, lB = 0.0f;
    bf16_t* prowA = &plds[w][q15][0];
    bf16_t* prowB = &plds[w][16 + q15][0];

    bf16x8 kbuf0[8], kbuf1[8];   // two static K-tile buffers (no runtime idx)

    auto loadK = [&](bf16x8* buf, int kb_) {
        #pragma unroll
        for (int sub = 0; sub < 4; ++sub) {
            const bf16_t* kp = kp0 + (size_t)(kb_ + sub * 16) * HD;
            buf[2 * sub]     = *(const bf16x8*)(kp);
            buf[2 * sub + 1] = *(const bf16x8*)(kp + 32);
        }
    };

    auto tile = [&](int kt, bf16x8* kf, bf16x8* nkf, bool pref) {
        const int kb = kt * 64;
        const unsigned long long mb = __ballot(mrow[kb + l] != 0);

        // S^T = K · Q^T for both q-sets from the prefetched K buffer
        f32x4 sA[4], sB[4];
        #pragma unroll
        for (int i = 0; i < 4; ++i) {
            sA[i] = (f32x4){0.f, 0.f, 0.f, 0.f};
            sB[i] = (f32x4){0.f, 0.f, 0.f, 0.f};
        }
        #pragma unroll
        for (int sub = 0; sub < 4; ++sub) {
            sA[sub] = MFMA16(kf[2 * sub],     qfA0, sA[sub]);
            sA[sub] = MFMA16(kf[2 * sub + 1], qfA1, sA[sub]);
            sB[sub] = MFMA16(kf[2 * sub],     qfB0, sB[sub]);
            sB[sub] = MFMA16(kf[2 * sub + 1], qfB1, sB[sub]);
        }

        // issue next tile's K loads now: covered by softmax + PV + next QK issue
        if (pref) loadK(nkf, kb + 64);

        // V fragments (consumed after softmax; latency covered by softmax)
        bf16x8 vf[8];
        #pragma unroll
        for (int ds = 0; ds < 4; ++ds) {
            const bf16_t* vp = vp0 + (size_t)(ds * 16) * S_LEN + kb;
            vf[ds]     = *(const bf16x8*)(vp);
            vf[ds + 4] = *(const bf16x8*)(vp + 32);
        }

        // masking only when some bit is off (uniform branch)
        if (mb != ~0ull) {
            #pragma unroll
            for (int sub = 0; sub < 4; ++sub)
                #pragma unroll
                for (int r = 0; r < 4; ++r) {
                    const int j = sub * 16 + g * 4 + r;
                    if (!((mb >> j) & 1ull)) { sA[sub][r] = NEG_L2; sB[sub][r] = NEG_L2; }
                }
        }

        // --- softmax, two independent chains (ILP) ---
        float pmA = -INFINITY, pmB = -INFINITY;
        #pragma unroll
        for (int sub = 0; sub < 4; ++sub)
            #pragma unroll
            for (int r = 0; r < 4; ++r) {
                pmA = fmaxf(pmA, sA[sub][r]);
                pmB = fmaxf(pmB, sB[sub][r]);
            }
        pmA = fmaxf(pmA, __shfl_xor(pmA, 16));
        pmB = fmaxf(pmB, __shfl_xor(pmB, 16));
        pmA = fmaxf(pmA, __shfl_xor(pmA, 32));
        pmB = fmaxf(pmB, __shfl_xor(pmB, 32));

        if (!__all(pmA <= mA + DEFER_THR)) {
            const float mnew = fmaxf(mA, pmA);
            const float corr = exp2f(mA - mnew);
            lA *= corr;
            float cr[4];
            #pragma unroll
            for (int r = 0; r < 4; ++r) cr[r] = __shfl(corr, g * 4 + r);
            #pragma unroll
            for (int ds = 0; ds < 4; ++ds)
                #pragma unroll
                for (int r = 0; r < 4; ++r) accA[ds][r] *= cr[r];
            mA = mnew;
        }
        if (!__all(pmB <= mB + DEFER_THR)) {
            const float mnew = fmaxf(mB, pmB);
            const float corr = exp2f(mB - mnew);
            lB *= corr;
            float cr[4];
            #pragma unroll
            for (int r = 0; r < 4; ++r) cr[r] = __shfl(corr, g * 4 + r);
            #pragma unroll
            for (int ds = 0; ds < 4; ++ds)
                #pragma unroll
                for (int r = 0; r < 4; ++r) accB[ds][r] *= cr[r];
            mB = mnew;
        }

        float tsA = 0.0f, tsB = 0.0f;
        #pragma unroll
        for (int sub = 0; sub < 4; ++sub) {
            bf16x4 pkA, pkB;
            #pragma unroll
            for (int r = 0; r < 4; ++r) {
                const float pa = exp2f(sA[sub][r] - mA);
                const float pb = exp2f(sB[sub][r] - mB);
                tsA += pa; tsB += pb;
                pkA[r] = (bf16_t)pa; pkB[r] = (bf16_t)pb;
            }
            *(bf16x4*)&prowA[sub * 16 + g * 4] = pkA;
            *(bf16x4*)&prowB[sub * 16 + g * 4] = pkB;
        }
        tsA += __shfl_xor(tsA, 16); tsB += __shfl_xor(tsB, 16);
        tsA += __shfl_xor(tsA, 32); tsB += __shfl_xor(tsB, 32);
        lA += tsA; lB += tsB;

        asm volatile("" ::: "memory");  // order P writes before P reads

        // O += P · V, both sets sharing vf
        #pragma unroll
        for (int c = 0; c < 2; ++c) {
            const bf16x4 aLo = *(const bf16x4*)&prowA[32 * c + g * 8];
            const bf16x4 aHi = *(const bf16x4*)&prowA[32 * c + g * 8 + 4];
            const bf16x4 bLo = *(const bf16x4*)&prowB[32 * c + g * 8];
            const bf16x4 bHi = *(const bf16x4*)&prowB[32 * c + g * 8 + 4];
            bf16x8 pfA, pfB;
            #pragma unroll
            for (int i = 0; i < 4; ++i) {
                pfA[i] = aLo[i]; pfA[i + 4] = aHi[i];
                pfB[i] = bLo[i]; pfB[i + 4] = bHi[i];
            }
            #pragma unroll
            for (int ds = 0; ds < 4; ++ds) {
                accA[ds] = MFMA16(pfA, vf[ds + 4 * c], accA[ds]);
                accB[ds] = MFMA16(pfB, vf[ds + 4 * c], accB[ds]);
            }
        }
        asm volatile("" ::: "memory");  // P reads before next-iter writes
    };

    loadK(kbuf0, 0);
    for (int kt = 0; kt < 32; kt += 2) {
        tile(kt,     kbuf0, kbuf1, true);
        tile(kt + 1, kbuf1, kbuf0, kt + 1 < 31);
    }

    // normalize and write AO[n][s][h][d] via per-wave LDS transpose
    float liA[4], liB[4];
    #pragma unroll
    for (int r = 0; r < 4; ++r) {
        liA[r] = 1.0f / __shfl(lA, g * 4 + r);
        liB[r] = 1.0f / __shfl(lB, g * 4 + r);
    }
    #pragma unroll
    for (int ds = 0; ds < 4; ++ds)
        #pragma unroll
        for (int r = 0; r < 4; ++r) {
            plds[w][g * 4 + r][ds * 16 + q15]      = (bf16_t)(accA[ds][r] * liA[r]);
            plds[w][16 + g * 4 + r][ds * 16 + q15] = (bf16_t)(accB[ds][r] * liB[r]);
        }
    asm volatile("" ::: "memory");

    const int qrow = l >> 2, seg = (l & 3) * 16;
    #pragma unroll
    for (int set = 0; set < 2; ++set) {
        const bf16x8 o0 = *(const bf16x8*)&plds[w][set * 16 + qrow][seg];
        const bf16x8 o1 = *(const bf16x8*)&plds[w][set * 16 + qrow][seg + 8];
        bf16_t* op = AO + (size_t)(n * S_LEN + qb + set * 16 + qrow) * EMB + h * HD + seg;
        *(bf16x8*)(op) = o0;
        *(bf16x8*)(op + 8) = o1;
    }
}

// --------------------------------------------------------------------------
// Kernel 3: out = AO @ Wo^T + bo.  M=4096, N=1024, K=1024. fp32 out.
// 128x64 tile (512 blocks), BK=64, 4 waves (2x2, each 64x32).
// --------------------------------------------------------------------------
__global__ __launch_bounds__(256) void outproj_kernel(
    const bf16_t* __restrict__ X, const float* __restrict__ Wo,
    const float* __restrict__ bo, float* __restrict__ out)
{
    __shared__ bf16_t Xs[128 * 64];
    __shared__ bf16_t Ws[64 * 64];
    const int tid = threadIdx.x;
    const int w = tid >> 6, l = tid & 63, g = l >> 4, q15 = l & 15;
    const int m0 = (blockIdx.x >> 4) * 128;
    const int n0 = (blockIdx.x & 15) * 64;
    const int wm = (w >> 1) * 64, wn = (w & 1) * 32;

    f32x4 acc[4][2];
    #pragma unroll
    for (int i = 0; i < 4; ++i)
        #pragma unroll
        for (int j = 0; j < 2; ++j) acc[i][j] = (f32x4){0.f, 0.f, 0.f, 0.f};

    for (int k0 = 0; k0 < EMB; k0 += 64) {
        __syncthreads();
        #pragma unroll
        for (int j = 0; j < 4; ++j) {
            const int cid = tid + 256 * j;
            const int r = cid >> 3, pc = cid & 7;
            const int sw = (pc ^ (r & 7)) * 8;
            *(bf16x8*)&Xs[r * 64 + sw] =
                *(const bf16x8*)(X + (size_t)(m0 + r) * EMB + k0 + pc * 8);
        }
        #pragma unroll
        for (int j = 0; j < 2; ++j) {
            const int cid = tid + 256 * j;
            const int r = cid >> 3, pc = cid & 7;
            const int sw = (pc ^ (r & 7)) * 8;
            *(bf16x8*)&Ws[r * 64 + sw] =
                load8_cvt(Wo + (size_t)(n0 + r) * EMB + k0 + pc * 8);
        }
        __syncthreads();
        #pragma unroll
        for (int c = 0; c < 2; ++c) {
            bf16x8 av[4], bv[2];
            #pragma unroll
            for (int mt = 0; mt < 4; ++mt) {
                const int r = wm + mt * 16 + q15;
                av[mt] = *(const bf16x8*)&Xs[r * 64 + (((4 * c + g) ^ (r & 7)) * 8)];
            }
            #pragma unroll
            for (int nt = 0; nt < 2; ++nt) {
                const int r = wn + nt * 16 + q15;
                bv[nt] = *(const bf16x8*)&Ws[r * 64 + (((4 * c + g) ^ (r & 7)) * 8)];
            }
            #pragma unroll
            for (int mt = 0; mt < 4; ++mt)
                #pragma unroll
                for (int nt = 0; nt < 2; ++nt)
                    acc[mt][nt] = MFMA16(av[mt], bv[nt], acc[mt][nt]);
        }
    }

    float bias[2];
    #pragma unroll
    for (int nt = 0; nt < 2; ++nt) bias[nt] = bo[n0 + wn + nt * 16 + q15];
    #pragma unroll
    for (int mt = 0; mt < 4; ++mt)
        #pragma unroll
        for (int nt = 0; nt < 2; ++nt)
            #pragma unroll
            for (int r = 0; r < 4; ++r)
                out[(size_t)(m0 + wm + mt * 16 + g * 4 + r) * EMB + n0 + wn + nt * 16 + q15]
                    = acc[mt][nt][r] + bias[nt];
}

// --------------------------------------------------------------------------
extern "C" void kernel_launch(void* const* d_in, const int* in_sizes, int n_in,
                              void* d_out, int out_size, void* d_ws, size_t ws_size,
                              hipStream_t stream) {
    const float* values  = (const float*)d_in[0];
    const float* keys    = (const float*)d_in[1];
    const float* queries = (const float*)d_in[2];
    const int*   mask    = (const int*)d_in[3];
    const float* Wv      = (const float*)d_in[4];
    const float* Wk      = (const float*)d_in[5];
    const float* Wq      = (const float*)d_in[6];
    const float* Wo      = (const float*)d_in[7];
    const float* bo      = (const float*)d_in[8];
    float* out = (float*)d_out;

    // ws layout (bf16 elems): Qp[0,4M) Kp[4M,8M) VpT[8M,12M) AO[12M,16M)
    bf16_t* Qp  = (bf16_t*)d_ws;
    bf16_t* Kp  = Qp  + (size_t)4194304;
    bf16_t* VpT = Kp  + (size_t)4194304;
    bf16_t* AO  = VpT + (size_t)4194304;

    proj_kernel<<<3072, 256, 0, stream>>>(values, keys, queries, Wv, Wk, Wq, Qp, Kp, VpT);
    attn_kernel<<<512, 256, 0, stream>>>(Qp, Kp, VpT, mask, AO);
    outproj_kernel<<<512, 256, 0, stream>>>(AO, Wo, bo, out);
}

// Round 6
// 176.025 us; speedup vs baseline: 1.8048x; 1.0004x over previous
//
#include <hip/hip_runtime.h>

typedef __bf16 bf16_t;
typedef __bf16 bf16x8 __attribute__((ext_vector_type(8)));
typedef __bf16 bf16x4 __attribute__((ext_vector_type(4)));
typedef float f32x4 __attribute__((ext_vector_type(4)));

#define MFMA16(a, b, c) __builtin_amdgcn_mfma_f32_16x16x32_bf16((a), (b), (c), 0, 0, 0)

namespace {
constexpr int S_LEN = 2048;
constexpr int EMB   = 1024;
constexpr int HEADS = 16;
constexpr int HD    = 64;
// Q pre-scaled by log2(e)/sqrt(EMB): scores are in the log2 domain.
constexpr float Q_PRESCALE = 1.44269504088896340736f / 32.0f;
constexpr float NEG_L2     = -4.5084e18f;   // -1e20 * log2(e)/32
constexpr float DEFER_THR  = 8.0f;          // skip rescale if growth <= 8 (p <= 256)
}

// load 8 contiguous fp32 and round to bf16x8
__device__ __forceinline__ bf16x8 load8_cvt(const float* __restrict__ p) {
    const f32x4 a = *(const f32x4*)p;
    const f32x4 b = *(const f32x4*)(p + 4);
    bf16x8 r;
    r[0] = (bf16_t)a[0]; r[1] = (bf16_t)a[1]; r[2] = (bf16_t)a[2]; r[3] = (bf16_t)a[3];
    r[4] = (bf16_t)b[0]; r[5] = (bf16_t)b[1]; r[6] = (bf16_t)b[2]; r[7] = (bf16_t)b[3];
    return r;
}

// --------------------------------------------------------------------------
// Kernel 1: per-head projections (fp32 in -> bf16 out).
//   mat 0: Qp[nh][s][d]  = (queries @ Wq^T) * Q_PRESCALE
//   mat 1: Kp[nh][s][d]  = keys @ Wk^T
//   mat 2: VpT[nh][d][s] = (values @ Wv^T)^T
// --------------------------------------------------------------------------
__global__ __launch_bounds__(256) void proj_kernel(
    const float* __restrict__ values, const float* __restrict__ keys,
    const float* __restrict__ queries,
    const float* __restrict__ Wv, const float* __restrict__ Wk,
    const float* __restrict__ Wq,
    bf16_t* __restrict__ Qp, bf16_t* __restrict__ Kp, bf16_t* __restrict__ VpT)
{
    const int tid = threadIdx.x;
    const int w = tid >> 6, l = tid & 63, g = l >> 4, q15 = l & 15;
    const int b   = blockIdx.x;
    const int mat = b >> 10;          // 0=Q, 1=K, 2=V
    const int rem = b & 1023;
    const int h   = rem >> 6;
    const int t0  = (((rem & 63) << 2) + w) << 4;
    const int n   = t0 >> 11;
    const int s0  = t0 & 2047;

    if (mat < 2) {
        const float* X = (mat == 0) ? queries : keys;
        const float* W = (mat == 0) ? Wq : Wk;
        const float scl = (mat == 0) ? Q_PRESCALE : 1.0f;
        bf16_t* O = ((mat == 0) ? Qp : Kp) + (size_t)(n * HEADS + h) * S_LEN * HD;
        const float* xr = X + (size_t)(t0 + q15) * EMB + h * HD + g * 8;
        bf16x8 a0 = load8_cvt(xr);
        bf16x8 a1 = load8_cvt(xr + 32);
        f32x4 acc[4];
        #pragma unroll
        for (int nt = 0; nt < 4; ++nt) acc[nt] = (f32x4){0.f, 0.f, 0.f, 0.f};
        #pragma unroll
        for (int nt = 0; nt < 4; ++nt) {
            const float* wr = W + (nt * 16 + q15) * HD + g * 8;
            bf16x8 b0 = load8_cvt(wr);
            bf16x8 b1 = load8_cvt(wr + 32);
            acc[nt] = MFMA16(a0, b0, acc[nt]);
            acc[nt] = MFMA16(a1, b1, acc[nt]);
        }
        #pragma unroll
        for (int nt = 0; nt < 4; ++nt)
            #pragma unroll
            for (int r = 0; r < 4; ++r)
                O[(size_t)(s0 + g * 4 + r) * HD + nt * 16 + q15] = (bf16_t)(acc[nt][r] * scl);
    } else {
        const float* xr = values + (size_t)(t0 + q15) * EMB + h * HD + g * 8;
        bf16x8 b0 = load8_cvt(xr);
        bf16x8 b1 = load8_cvt(xr + 32);
        bf16_t* O = VpT + (size_t)(n * HEADS + h) * HD * S_LEN;
        f32x4 acc[4];
        #pragma unroll
        for (int et = 0; et < 4; ++et) acc[et] = (f32x4){0.f, 0.f, 0.f, 0.f};
        #pragma unroll
        for (int et = 0; et < 4; ++et) {
            const float* wr = Wv + (et * 16 + q15) * HD + g * 8;
            bf16x8 a0 = load8_cvt(wr);
            bf16x8 a1 = load8_cvt(wr + 32);
            acc[et] = MFMA16(a0, b0, acc[et]);
            acc[et] = MFMA16(a1, b1, acc[et]);
        }
        #pragma unroll
        for (int et = 0; et < 4; ++et)
            #pragma unroll
            for (int r = 0; r < 4; ++r)
                O[(size_t)(et * 16 + g * 4 + r) * S_LEN + s0 + q15] = (bf16_t)acc[et][r];
    }
}

// --------------------------------------------------------------------------
// Kernel 2: flash attention, 32 q-rows per wave (two independent 16-row
// sets A/B sharing K and V fragment loads), K register-double-buffered.
// Mask handling hoisted to a pre-loop (wave-uniform 64-bit table): the
// steady-state tile body has NO global loads besides K/V fragments and
// no vmcnt(0)-drain, so prefetches stay in flight across tiles.
// Swapped QK^T: q = lane&15, softmax reduce = 2 shfl_xor per set.
// --------------------------------------------------------------------------
__global__ __launch_bounds__(256, 2) void attn_kernel(
    const bf16_t* __restrict__ Qp, const bf16_t* __restrict__ Kp,
    const bf16_t* __restrict__ VpT, const int* __restrict__ mask,
    bf16_t* __restrict__ AO)
{
    __shared__ bf16_t plds[4][32][72];   // per-wave P rows; row stride 144B = 9*16B
    const int tid = threadIdx.x;
    const int w = tid >> 6, l = tid & 63, g = l >> 4, q15 = l & 15;
    const int bid = blockIdx.x;
    const int nh = bid & 31, qt = bid >> 5;   // qt in [0,16)
    const int n = nh >> 4, h = nh & 15;
    const size_t hb = (size_t)nh * S_LEN * HD;
    const int qb = qt * 128 + w * 32;

    // Q B-fragments for both 16-row sets (col = q = lane&15, k = d)
    const bf16_t* qrA = Qp + hb + (size_t)(qb + q15) * HD + g * 8;
    const bf16_t* qrB = qrA + 16 * HD;
    const bf16x8 qfA0 = *(const bf16x8*)(qrA);
    const bf16x8 qfA1 = *(const bf16x8*)(qrA + 32);
    const bf16x8 qfB0 = *(const bf16x8*)(qrB);
    const bf16x8 qfB1 = *(const bf16x8*)(qrB + 32);

    const int* __restrict__ mrow = mask + n * S_LEN;
    // per-lane K/V base pointers
    const bf16_t* kp0 = Kp  + hb + (size_t)q15 * HD + g * 8;
    const bf16_t* vp0 = VpT + hb + (size_t)q15 * S_LEN + g * 8;

    // ---- pre-loop mask scan: bit pair (2t,2t+1) of maskbal != 0 iff tile t
    // has any masked-out key. Lane l scans mask[64*(l>>1)+32*(l&1) .. +31].
    bool anyZero = false;
    {
        const int* mp = mrow + (l >> 1) * 64 + (l & 1) * 32;
        #pragma unroll
        for (int j = 0; j < 8; ++j) {
            const int4 mv = *(const int4*)(mp + 4 * j);
            anyZero |= (mv.x == 0) | (mv.y == 0) | (mv.z == 0) | (mv.w == 0);
        }
    }
    const unsigned long long maskbal = __ballot(anyZero);

    f32x4 accA[4], accB[4];
    #pragma unroll
    for (int i = 0; i < 4; ++i) {
        accA[i] = (f32x4){0.f, 0.f, 0.f, 0.f};
        accB[i] = (f32x4){0.f, 0.f, 0.f, 0.f};
    }
    float mA = -INFINITY, lA = 0.0f;
    float mB = -INFINITY, lB = 0.0f;
    bf16_t* prowA = &plds[w][q15][0];
    bf16_t* prowB = &plds[w][16 + q15][0];

    bf16x8 kbuf0[8], kbuf1[8];   // two static K-tile buffers (no runtime idx)

    auto loadK = [&](bf16x8* buf, int kb_) {
        #pragma unroll
        for (int sub = 0; sub < 4; ++sub) {
            const bf16_t* kp = kp0 + (size_t)(kb_ + sub * 16) * HD;
            buf[2 * sub]     = *(const bf16x8*)(kp);
            buf[2 * sub + 1] = *(const bf16x8*)(kp + 32);
        }
    };

    auto tile = [&](int kt, bf16x8* kf, bf16x8* nkf, bool pref) {
        const int kb = kt * 64;

        // S^T = K · Q^T for both q-sets from the prefetched K buffer
        f32x4 sA[4], sB[4];
        #pragma unroll
        for (int i = 0; i < 4; ++i) {
            sA[i] = (f32x4){0.f, 0.f, 0.f, 0.f};
            sB[i] = (f32x4){0.f, 0.f, 0.f, 0.f};
        }
        #pragma unroll
        for (int sub = 0; sub < 4; ++sub) {
            sA[sub] = MFMA16(kf[2 * sub],     qfA0, sA[sub]);
            sA[sub] = MFMA16(kf[2 * sub + 1], qfA1, sA[sub]);
            sB[sub] = MFMA16(kf[2 * sub],     qfB0, sB[sub]);
            sB[sub] = MFMA16(kf[2 * sub + 1], qfB1, sB[sub]);
        }

        // issue next tile's K loads now: covered by softmax + PV + next QK issue
        if (pref) loadK(nkf, kb + 64);

        // V fragments (consumed after softmax; latency covered by softmax)
        bf16x8 vf[8];
        #pragma unroll
        for (int ds = 0; ds < 4; ++ds) {
            const bf16_t* vp = vp0 + (size_t)(ds * 16) * S_LEN + kb;
            vf[ds]     = *(const bf16x8*)(vp);
            vf[ds + 4] = *(const bf16x8*)(vp + 32);
        }

        // masking: wave-uniform scalar test, rare path only
        if ((maskbal >> (2 * kt)) & 3ull) {
            const unsigned long long mb = __ballot(mrow[kb + l] != 0);
            #pragma unroll
            for (int sub = 0; sub < 4; ++sub)
                #pragma unroll
                for (int r = 0; r < 4; ++r) {
                    const int j = sub * 16 + g * 4 + r;
                    if (!((mb >> j) & 1ull)) { sA[sub][r] = NEG_L2; sB[sub][r] = NEG_L2; }
                }
        }

        // --- softmax, two independent chains (ILP) ---
        float pmA = -INFINITY, pmB = -INFINITY;
        #pragma unroll
        for (int sub = 0; sub < 4; ++sub)
            #pragma unroll
            for (int r = 0; r < 4; ++r) {
                pmA = fmaxf(pmA, sA[sub][r]);
                pmB = fmaxf(pmB, sB[sub][r]);
            }
        pmA = fmaxf(pmA, __shfl_xor(pmA, 16));
        pmB = fmaxf(pmB, __shfl_xor(pmB, 16));
        pmA = fmaxf(pmA, __shfl_xor(pmA, 32));
        pmB = fmaxf(pmB, __shfl_xor(pmB, 32));

        if (!__all(pmA <= mA + DEFER_THR)) {
            const float mnew = fmaxf(mA, pmA);
            const float corr = exp2f(mA - mnew);
            lA *= corr;
            float cr[4];
            #pragma unroll
            for (int r = 0; r < 4; ++r) cr[r] = __shfl(corr, g * 4 + r);
            #pragma unroll
            for (int ds = 0; ds < 4; ++ds)
                #pragma unroll
                for (int r = 0; r < 4; ++r) accA[ds][r] *= cr[r];
            mA = mnew;
        }
        if (!__all(pmB <= mB + DEFER_THR)) {
            const float mnew = fmaxf(mB, pmB);
            const float corr = exp2f(mB - mnew);
            lB *= corr;
            float cr[4];
            #pragma unroll
            for (int r = 0; r < 4; ++r) cr[r] = __shfl(corr, g * 4 + r);
            #pragma unroll
            for (int ds = 0; ds < 4; ++ds)
                #pragma unroll
                for (int r = 0; r < 4; ++r) accB[ds][r] *= cr[r];
            mB = mnew;
        }

        float tsA = 0.0f, tsB = 0.0f;
        #pragma unroll
        for (int sub = 0; sub < 4; ++sub) {
            bf16x4 pkA, pkB;
            #pragma unroll
            for (int r = 0; r < 4; ++r) {
                const float pa = exp2f(sA[sub][r] - mA);
                const float pb = exp2f(sB[sub][r] - mB);
                tsA += pa; tsB += pb;
                pkA[r] = (bf16_t)pa; pkB[r] = (bf16_t)pb;
            }
            *(bf16x4*)&prowA[sub * 16 + g * 4] = pkA;
            *(bf16x4*)&prowB[sub * 16 + g * 4] = pkB;
        }
        tsA += __shfl_xor(tsA, 16); tsB += __shfl_xor(tsB, 16);
        tsA += __shfl_xor(tsA, 32); tsB += __shfl_xor(tsB, 32);
        lA += tsA; lB += tsB;

        asm volatile("" ::: "memory");  // order P writes before P reads

        // O += P · V, both sets sharing vf; P read as one ds_read_b128
        #pragma unroll
        for (int c = 0; c < 2; ++c) {
            const bf16x8 pfA = *(const bf16x8*)&prowA[32 * c + g * 8];
            const bf16x8 pfB = *(const bf16x8*)&prowB[32 * c + g * 8];
            #pragma unroll
            for (int ds = 0; ds < 4; ++ds) {
                accA[ds] = MFMA16(pfA, vf[ds + 4 * c], accA[ds]);
                accB[ds] = MFMA16(pfB, vf[ds + 4 * c], accB[ds]);
            }
        }
        asm volatile("" ::: "memory");  // P reads before next-iter writes
    };

    loadK(kbuf0, 0);
    for (int kt = 0; kt < 32; kt += 2) {
        tile(kt,     kbuf0, kbuf1, true);
        tile(kt + 1, kbuf1, kbuf0, kt + 1 < 31);
    }

    // normalize and write AO[n][s][h][d] via per-wave LDS transpose
    float liA[4], liB[4];
    #pragma unroll
    for (int r = 0; r < 4; ++r) {
        liA[r] = 1.0f / __shfl(lA, g * 4 + r);
        liB[r] = 1.0f / __shfl(lB, g * 4 + r);
    }
    #pragma unroll
    for (int ds = 0; ds < 4; ++ds)
        #pragma unroll
        for (int r = 0; r < 4; ++r) {
            plds[w][g * 4 + r][ds * 16 + q15]      = (bf16_t)(accA[ds][r] * liA[r]);
            plds[w][16 + g * 4 + r][ds * 16 + q15] = (bf16_t)(accB[ds][r] * liB[r]);
        }
    asm volatile("" ::: "memory");

    const int qrow = l >> 2, seg = (l & 3) * 16;
    #pragma unroll
    for (int set = 0; set < 2; ++set) {
        const bf16x8 o0 = *(const bf16x8*)&plds[w][set * 16 + qrow][seg];
        const bf16x8 o1 = *(const bf16x8*)&plds[w][set * 16 + qrow][seg + 8];
        bf16_t* op = AO + (size_t)(n * S_LEN + qb + set * 16 + qrow) * EMB + h * HD + seg;
        *(bf16x8*)(op) = o0;
        *(bf16x8*)(op + 8) = o1;
    }
}

// --------------------------------------------------------------------------
// Kernel 3: out = AO @ Wo^T + bo.  M=4096, N=1024, K=1024. fp32 out.
// 128x64 tile (512 blocks), BK=64, 4 waves (2x2, each 64x32).
// --------------------------------------------------------------------------
__global__ __launch_bounds__(256) void outproj_kernel(
    const bf16_t* __restrict__ X, const float* __restrict__ Wo,
    const float* __restrict__ bo, float* __restrict__ out)
{
    __shared__ bf16_t Xs[128 * 64];
    __shared__ bf16_t Ws[64 * 64];
    const int tid = threadIdx.x;
    const int w = tid >> 6, l = tid & 63, g = l >> 4, q15 = l & 15;
    const int m0 = (blockIdx.x >> 4) * 128;
    const int n0 = (blockIdx.x & 15) * 64;
    const int wm = (w >> 1) * 64, wn = (w & 1) * 32;

    f32x4 acc[4][2];
    #pragma unroll
    for (int i = 0; i < 4; ++i)
        #pragma unroll
        for (int j = 0; j < 2; ++j) acc[i][j] = (f32x4){0.f, 0.f, 0.f, 0.f};

    for (int k0 = 0; k0 < EMB; k0 += 64) {
        __syncthreads();
        #pragma unroll
        for (int j = 0; j < 4; ++j) {
            const int cid = tid + 256 * j;
            const int r = cid >> 3, pc = cid & 7;
            const int sw = (pc ^ (r & 7)) * 8;
            *(bf16x8*)&Xs[r * 64 + sw] =
                *(const bf16x8*)(X + (size_t)(m0 + r) * EMB + k0 + pc * 8);
        }
        #pragma unroll
        for (int j = 0; j < 2; ++j) {
            const int cid = tid + 256 * j;
            const int r = cid >> 3, pc = cid & 7;
            const int sw = (pc ^ (r & 7)) * 8;
            *(bf16x8*)&Ws[r * 64 + sw] =
                load8_cvt(Wo + (size_t)(n0 + r) * EMB + k0 + pc * 8);
        }
        __syncthreads();
        #pragma unroll
        for (int c = 0; c < 2; ++c) {
            bf16x8 av[4], bv[2];
            #pragma unroll
            for (int mt = 0; mt < 4; ++mt) {
                const int r = wm + mt * 16 + q15;
                av[mt] = *(const bf16x8*)&Xs[r * 64 + (((4 * c + g) ^ (r & 7)) * 8)];
            }
            #pragma unroll
            for (int nt = 0; nt < 2; ++nt) {
                const int r = wn + nt * 16 + q15;
                bv[nt] = *(const bf16x8*)&Ws[r * 64 + (((4 * c + g) ^ (r & 7)) * 8)];
            }
            #pragma unroll
            for (int mt = 0; mt < 4; ++mt)
                #pragma unroll
                for (int nt = 0; nt < 2; ++nt)
                    acc[mt][nt] = MFMA16(av[mt], bv[nt], acc[mt][nt]);
        }
    }

    float bias[2];
    #pragma unroll
    for (int nt = 0; nt < 2; ++nt) bias[nt] = bo[n0 + wn + nt * 16 + q15];
    #pragma unroll
    for (int mt = 0; mt < 4; ++mt)
        #pragma unroll
        for (int nt = 0; nt < 2; ++nt)
            #pragma unroll
            for (int r = 0; r < 4; ++r)
                out[(size_t)(m0 + wm + mt * 16 + g * 4 + r) * EMB + n0 + wn + nt * 16 + q15]
                    = acc[mt][nt][r] + bias[nt];
}

// --------------------------------------------------------------------------
extern "C" void kernel_launch(void* const* d_in, const int* in_sizes, int n_in,
                              void* d_out, int out_size, void* d_ws, size_t ws_size,
                              hipStream_t stream) {
    const float* values  = (const float*)d_in[0];
    const float* keys    = (const float*)d_in[1];
    const float* queries = (const float*)d_in[2];
    const int*   mask    = (const int*)d_in[3];
    const float* Wv      = (const float*)d_in[4];
    const float* Wk      = (const float*)d_in[5];
    const float* Wq      = (const float*)d_in[6];
    const float* Wo      = (const float*)d_in[7];
    const float* bo      = (const float*)d_in[8];
    float* out = (float*)d_out;

    // ws layout (bf16 elems): Qp[0,4M) Kp[4M,8M) VpT[8M,12M) AO[12M,16M)
    bf16_t* Qp  = (bf16_t*)d_ws;
    bf16_t* Kp  = Qp  + (size_t)4194304;
    bf16_t* VpT = Kp  + (size_t)4194304;
    bf16_t* AO  = VpT + (size_t)4194304;

    proj_kernel<<<3072, 256, 0, stream>>>(values, keys, queries, Wv, Wk, Wq, Qp, Kp, VpT);
    attn_kernel<<<512, 256, 0, stream>>>(Qp, Kp, VpT, mask, AO);
    outproj_kernel<<<512, 256, 0, stream>>>(AO, Wo, bo, out);
}